// Round 6
// baseline (327.621 us; speedup 1.0000x reference)
//
#include <hip/hip_runtime.h>

#define NB 65536
#define NATOM 256
#define NA 64
#define NM 128
#define TRAJ_SZ (NB*NATOM*3)   // 50331648
#define REF_SZ  (NATOM*3)      // 768
#define SLOT_F  384            // floats per batch output slot (1536 bytes)
#define ROW_F   (NATOM*3)      // 768 floats (3072 B) per batch traj row
#define NBB     8              // batches per block-chunk (4 waves x 2)
#define NCHUNK  (NB/NBB)       // 8192 chunks
#define GRID    2048           // persistent-ish: each block loops 4 chunks

__device__ __forceinline__ float bf2f(unsigned short u) {
    union { unsigned int i; float f; } v; v.i = ((unsigned int)u) << 16; return v.f;
}
// expand a dword holding two bf16 into two floats (2 VALU)
__device__ __forceinline__ float2 bf2x2(unsigned int u) {
    union { unsigned int i; float f; } lo, hi;
    lo.i = u << 16; hi.i = u & 0xffff0000u;
    return make_float2(lo.f, hi.f);
}

// Wave-local LDS handoff: drain own DS ops, forbid compiler reordering.
// (lgkmcnt is per-wave; all 64 lanes' parts of a DS instruction retire together)
__device__ __forceinline__ void wave_lds_fence() {
    asm volatile("s_waitcnt lgkmcnt(0)" ::: "memory");
}

// ---- DPP wave reduction (VALU-only; no DS-pipe traffic) ----
// gfx9 pattern (rocPRIM): row_shr 1/2/4/8 then row_bcast15/31.
// bound_ctrl=true -> invalid source lanes yield 0. Full sum valid in lane 63.
template<int CTRL>
__device__ __forceinline__ float dpp_add(float x) {
    int m = __builtin_amdgcn_update_dpp(0, __float_as_int(x), CTRL, 0xf, 0xf, true);
    return x + __int_as_float(m);
}
__device__ __forceinline__ float wave_sum63(float x) {
    x = dpp_add<0x111>(x);   // row_shr:1
    x = dpp_add<0x112>(x);   // row_shr:2
    x = dpp_add<0x114>(x);   // row_shr:4
    x = dpp_add<0x118>(x);   // row_shr:8
    x = dpp_add<0x142>(x);   // row_bcast:15
    x = dpp_add<0x143>(x);   // row_bcast:31
    return x;                // total in lane 63
}
__device__ __forceinline__ float wave_sum_bcast(float x) {
    return __int_as_float(__builtin_amdgcn_readlane(__float_as_int(wave_sum63(x)), 63));
}
template<int CTRL>
__device__ __forceinline__ float dpp_max(float x) {
    int m = __builtin_amdgcn_update_dpp(0, __float_as_int(x), CTRL, 0xf, 0xf, true);
    return fmaxf(x, __int_as_float(m));
}
__device__ __forceinline__ float wave_max_bcast(float x) {   // x >= 0 assumed
    x = dpp_max<0x111>(x);
    x = dpp_max<0x112>(x);
    x = dpp_max<0x114>(x);
    x = dpp_max<0x118>(x);
    x = dpp_max<0x142>(x);
    x = dpp_max<0x143>(x);
    return __int_as_float(__builtin_amdgcn_readlane(__float_as_int(x), 63));
}

// Per-wave storage-dtype probe on 64 fixed traj locations (low halfword of each
// 4-byte group, viewed as bf16):
//   bf16 storage             -> real N(0,1) bf16 values: max in ~[2, 6]    -> 0
//   fp32 full precision      -> random exponent bits: max huge (or NaN)    -> 1
//   fp32 w/ bf16-ed values   -> low mantissa halves all zero: max == 0     -> 1
__device__ __forceinline__ int detect_f32(const unsigned short* __restrict__ traj_u) {
    int lane = threadIdx.x & 63;
    float mx = wave_max_bcast(fabsf(bf2f(traj_u[2 * lane])));
    return (mx > 0.5f && mx < 100.f) ? 0 : 1;
}

// 3x3 Kabsch on one thread: reads P+xc packed in 3 float4, returns rot+xc packed.
__device__ __forceinline__ void kabsch3(float4 A, float4 Bq, float4 Cq,
                                        float4* O0, float4* O1, float4* O2) {
    float p00=A.x, p01=A.y, p02=A.z, p10=A.w;
    float p11=Bq.x, p12=Bq.y, p20=Bq.z, p21=Bq.w;
    float p22=Cq.x;
    float s00 = p00*p00 + p10*p10 + p20*p20;
    float s01 = p00*p01 + p10*p11 + p20*p21;
    float s02 = p00*p02 + p10*p12 + p20*p22;
    float s11 = p01*p01 + p11*p11 + p21*p21;
    float s12 = p01*p02 + p11*p12 + p21*p22;
    float s22 = p02*p02 + p12*p12 + p22*p22;
    float v00=1.f,v01=0.f,v02=0.f, v10=0.f,v11=1.f,v12=0.f, v20=0.f,v21=0.f,v22=1.f;
#define JROT(SPP,SQQ,SPQ,SRP,SRQ,VA,VB,VC,VD,VE,VF) { \
    float apq = SPQ; \
    if (apq != 0.0f) { \
        float tau = (SQQ - SPP) / (2.0f*apq); \
        float t = (tau >= 0.0f ? 1.0f : -1.0f) / (fabsf(tau) + sqrtf(1.0f + tau*tau)); \
        float c = 1.0f / sqrtf(1.0f + t*t); \
        float sn = t*c; \
        SPP -= t*apq; SQQ += t*apq; SPQ = 0.0f; \
        float tp = SRP; SRP = c*tp - sn*SRQ; SRQ = sn*tp + c*SRQ; \
        tp = VA; VA = c*tp - sn*VB; VB = sn*tp + c*VB; \
        tp = VC; VC = c*tp - sn*VD; VD = sn*tp + c*VD; \
        tp = VE; VE = c*tp - sn*VF; VF = sn*tp + c*VF; \
    } }
    #pragma unroll
    for (int sweep = 0; sweep < 5; ++sweep) {
        JROT(s00,s11,s01, s02,s12, v00,v01, v10,v11, v20,v21);
        JROT(s00,s22,s02, s01,s12, v00,v02, v10,v12, v20,v22);
        JROT(s11,s22,s12, s01,s02, v01,v02, v11,v12, v21,v22);
    }
#undef JROT
    float v1x,v1y,v1z, v2x,v2y,v2z;
    if (s00 <= s11 && s00 <= s22) {
        v1x=v01; v1y=v11; v1z=v21;  v2x=v02; v2y=v12; v2z=v22;
    } else if (s11 <= s22) {
        v1x=v02; v1y=v12; v1z=v22;  v2x=v00; v2y=v10; v2z=v20;
    } else {
        v1x=v00; v1y=v10; v1z=v20;  v2x=v01; v2y=v11; v2z=v21;
    }
    float u1x = p00*v1x + p01*v1y + p02*v1z;
    float u1y = p10*v1x + p11*v1y + p12*v1z;
    float u1z = p20*v1x + p21*v1y + p22*v1z;
    float inv = 1.0f / sqrtf(u1x*u1x + u1y*u1y + u1z*u1z);
    u1x*=inv; u1y*=inv; u1z*=inv;
    float u2x = p00*v2x + p01*v2y + p02*v2z;
    float u2y = p10*v2x + p11*v2y + p12*v2z;
    float u2z = p20*v2x + p21*v2y + p22*v2z;
    float d = u2x*u1x + u2y*u1y + u2z*u1z;   // Gram-Schmidt
    u2x -= d*u1x; u2y -= d*u1y; u2z -= d*u1z;
    inv = 1.0f / sqrtf(u2x*u2x + u2y*u2y + u2z*u2z);
    u2x*=inv; u2y*=inv; u2z*=inv;
    float u3x = u1y*u2z - u1z*u2y;
    float u3y = u1z*u2x - u1x*u2z;
    float u3z = u1x*u2y - u1y*u2x;
    float v3x = v1y*v2z - v1z*v2y;
    float v3y = v1z*v2x - v1x*v2z;
    float v3z = v1x*v2y - v1y*v2x;
    *O0 = make_float4(u1x*v1x + u2x*v2x + u3x*v3x,
                      u1x*v1y + u2x*v2y + u3x*v3y,
                      u1x*v1z + u2x*v2z + u3x*v3z,
                      u1y*v1x + u2y*v2x + u3y*v3x);
    *O1 = make_float4(u1y*v1y + u2y*v2y + u3y*v3y,
                      u1y*v1z + u2y*v2z + u3y*v3z,
                      u1z*v1x + u2z*v2x + u3z*v3x,
                      u1z*v1y + u2z*v2y + u3z*v3y);
    *O2 = make_float4(u1z*v1z + u2z*v2z + u3z*v3z, Cq.y, Cq.z, Cq.w);
}

// Barrier-free fused kernel. Each wave owns 2 batches per chunk:
//   stage own 2 rows -> own LDS slice (coalesced dwordx4, prefetched one
//   chunk ahead) -> DPP-reduce P+xc (lane63 packs to pbuf) -> lanes 0,1 run
//   the two Kabsch SVDs -> apply + store direct to global.
// All LDS handoffs are intra-wave (lgkmcnt fence), zero __syncthreads.
__global__ __launch_bounds__(256) void k_fused(const unsigned short* __restrict__ traj_u,
                                               const unsigned short* __restrict__ refp_u,
                                               const int* __restrict__ align_idx,
                                               const int* __restrict__ nn_idx,
                                               float* __restrict__ out) {
    __shared__ float rowbuf[NBB][ROW_F];   // 24 KiB, wave w owns rows 2w,2w+1
    __shared__ float4 pbuf[NBB][3];        // P(9)+xc(3) packed; then rot+xc
    int tid  = threadIdx.x;
    int lane = tid & 63;
    int wid  = tid >> 6;
    int isf32 = detect_f32(traj_u);

    // per-wave constants
    int aidx = align_idx[lane];
    int n0 = nn_idx[lane];
    int n1 = nn_idx[lane + 64];
    float r0, r1, r2;
    if (isf32) {
        const float* rp = (const float*)refp_u;
        r0 = rp[aidx*3+0]; r1 = rp[aidx*3+1]; r2 = rp[aidx*3+2];
    } else {
        r0 = bf2f(refp_u[aidx*3+0]); r1 = bf2f(refp_u[aidx*3+1]); r2 = bf2f(refp_u[aidx*3+2]);
    }
    // center the reference selection (batch-independent)
    r0 -= wave_sum_bcast(r0) * (1.f/64.f);
    r1 -= wave_sum_bcast(r1) * (1.f/64.f);
    r2 -= wave_sum_bcast(r2) * (1.f/64.f);

    float4* dst4 = (float4*)&rowbuf[2*wid][0];   // my 2-row slice = 384 float4

#define REDUCE_SVD_APPLY(CHUNK)                                                 \
    {                                                                           \
        long c_ = (CHUNK);                                                      \
        _Pragma("unroll")                                                       \
        for (int s = 0; s < 2; ++s) {                                           \
            const float* row = rowbuf[2*wid + s];                               \
            float x0 = row[aidx*3+0];                                           \
            float x1 = row[aidx*3+1];                                           \
            float x2 = row[aidx*3+2];                                           \
            float p00 = wave_sum63(x0*r0), p01 = wave_sum63(x0*r1), p02 = wave_sum63(x0*r2); \
            float p10 = wave_sum63(x1*r0), p11 = wave_sum63(x1*r1), p12 = wave_sum63(x1*r2); \
            float p20 = wave_sum63(x2*r0), p21 = wave_sum63(x2*r1), p22 = wave_sum63(x2*r2); \
            float xc0 = wave_sum63(x0) * (1.f/64.f);                            \
            float xc1 = wave_sum63(x1) * (1.f/64.f);                            \
            float xc2 = wave_sum63(x2) * (1.f/64.f);                            \
            if (lane == 63) {                                                   \
                pbuf[2*wid+s][0] = make_float4(p00, p01, p02, p10);             \
                pbuf[2*wid+s][1] = make_float4(p11, p12, p20, p21);             \
                pbuf[2*wid+s][2] = make_float4(p22, xc0, xc1, xc2);             \
            }                                                                   \
        }                                                                       \
        wave_lds_fence();                                                       \
        if (lane < 2) {                                                         \
            int lb = 2*wid + lane;                                              \
            float4 O0, O1, O2;                                                  \
            kabsch3(pbuf[lb][0], pbuf[lb][1], pbuf[lb][2], &O0, &O1, &O2);      \
            pbuf[lb][0] = O0; pbuf[lb][1] = O1; pbuf[lb][2] = O2;               \
        }                                                                       \
        wave_lds_fence();                                                       \
        _Pragma("unroll")                                                       \
        for (int s = 0; s < 2; ++s) {                                           \
            int lb = 2*wid + s;                                                 \
            const float* row = rowbuf[lb];                                      \
            float4 A = pbuf[lb][0], Bq = pbuf[lb][1], Cq = pbuf[lb][2];         \
            float a0 = row[n0*3+0] - Cq.y;                                      \
            float a1 = row[n0*3+1] - Cq.z;                                      \
            float a2 = row[n0*3+2] - Cq.w;                                      \
            float b0 = row[n1*3+0] - Cq.y;                                      \
            float b1 = row[n1*3+1] - Cq.z;                                      \
            float b2 = row[n1*3+2] - Cq.w;                                      \
            float* dg = out + (c_*NBB + lb) * SLOT_F;                           \
            dg[3*lane+0] = a0*A.x + a1*A.w  + a2*Bq.z;                          \
            dg[3*lane+1] = a0*A.y + a1*Bq.x + a2*Bq.w;                          \
            dg[3*lane+2] = a0*A.z + a1*Bq.y + a2*Cq.x;                          \
            dg[3*(lane+64)+0] = b0*A.x + b1*A.w  + b2*Bq.z;                     \
            dg[3*(lane+64)+1] = b0*A.y + b1*Bq.x + b2*Bq.w;                     \
            dg[3*(lane+64)+2] = b0*A.z + b1*Bq.y + b2*Cq.x;                     \
        }                                                                       \
    }

    if (!isf32) {
        // ---- bf16 path: register-prefetched chunk loop ----
        long c = blockIdx.x;
        const uint4* src = (const uint4*)(traj_u + (c*NBB + 2*wid) * ROW_F);
        uint4 q0 = src[lane], q1 = src[lane+64], q2 = src[lane+128];
        while (c < NCHUNK) {
            long cn = c + (long)gridDim.x;
            // expand my 2 rows into my LDS slice (uint4 j -> float4 2j,2j+1)
            {
                uint4 qq0 = q0, qq1 = q1, qq2 = q2;
                #pragma unroll
                for (int k = 0; k < 3; ++k) {
                    uint4 q = (k == 0) ? qq0 : (k == 1) ? qq1 : qq2;
                    int j = lane + 64*k;
                    float2 a = bf2x2(q.x), b = bf2x2(q.y);
                    float2 cc = bf2x2(q.z), d = bf2x2(q.w);
                    dst4[2*j]   = make_float4(a.x, a.y, b.x, b.y);
                    dst4[2*j+1] = make_float4(cc.x, cc.y, d.x, d.y);
                }
            }
            // prefetch next chunk (latency hides under reduce+SVD+apply)
            if (cn < NCHUNK) {
                const uint4* s2 = (const uint4*)(traj_u + (cn*NBB + 2*wid) * ROW_F);
                q0 = s2[lane]; q1 = s2[lane+64]; q2 = s2[lane+128];
            }
            wave_lds_fence();
            REDUCE_SVD_APPLY(c);
            c = cn;
        }
    } else {
        // ---- f32 path (no prefetch; 6 dwordx4 per lane covers 2 rows) ----
        for (long c = blockIdx.x; c < NCHUNK; c += gridDim.x) {
            const float4* src = (const float4*)((const float*)traj_u + (c*NBB + 2*wid) * ROW_F);
            #pragma unroll
            for (int k = 0; k < 6; ++k) dst4[lane + 64*k] = src[lane + 64*k];
            wave_lds_fence();
            REDUCE_SVD_APPLY(c);
        }
    }
#undef REDUCE_SVD_APPLY
}

extern "C" void kernel_launch(void* const* d_in, const int* in_sizes, int n_in,
                              void* d_out, int out_size, void* d_ws, size_t ws_size,
                              hipStream_t stream) {
    // Assign inputs by element count (all four are distinct) — robust to ordering.
    const unsigned short* traj = (const unsigned short*)d_in[0];
    const unsigned short* refp = (const unsigned short*)d_in[1];
    const int* align_idx = (const int*)d_in[2];
    const int* nn_idx    = (const int*)d_in[3];
    for (int i = 0; i < n_in; ++i) {
        if      (in_sizes[i] == TRAJ_SZ) traj      = (const unsigned short*)d_in[i];
        else if (in_sizes[i] == REF_SZ)  refp      = (const unsigned short*)d_in[i];
        else if (in_sizes[i] == NA)      align_idx = (const int*)d_in[i];
        else if (in_sizes[i] == NM)      nn_idx    = (const int*)d_in[i];
    }
    float* out = (float*)d_out;

    k_fused<<<GRID, 256, 0, stream>>>(traj, refp, align_idx, nn_idx, out);
}